// Round 1
// baseline (124.910 us; speedup 1.0000x reference)
//
#include <hip/hip_runtime.h>

typedef _Float16 half4_t __attribute__((ext_vector_type(4)));
typedef _Float16 half8_t __attribute__((ext_vector_type(8)));
typedef float    f32x4   __attribute__((ext_vector_type(4)));

#define S_LEN 2048
#define DH    64
#define QBLK  128   // q rows per block (4 waves x 32)
#define QW    32    // q rows per wave
#define KVB   64    // kv rows per tile
#define SCALE 0.03125f  // 1/sqrt(1024), exact in f16

// XOR-swizzled LDS offset for a [row][128B] tile (m214 r268 fix for
// stride-128B column-slice bank conflicts). Bijective per 8-row stripe,
// preserves 16B alignment.
__device__ __forceinline__ int swz_off(int row, int byteInRow) {
    return row * 128 + (byteInRow ^ ((row & 7) << 4));
}

__global__ __launch_bounds__(256, 2)
void fattn_kernel(const float* __restrict__ Qg, const float* __restrict__ Kg,
                  const float* __restrict__ Vg, float* __restrict__ Og) {
    __shared__ __align__(16) char smem[16384];
    char* const Ks = smem;          // K tile  [64][64] f16, row-major, swizzled
    char* const Vs = smem + 8192;   // V^T tile [64 d][64 k] f16, swizzled

    const int bh  = (int)blockIdx.x;                     // 0..63 (b*16+h)
    const int qb  = (int)gridDim.y - 1 - (int)blockIdx.y; // heavy blocks first
    const int q0  = qb * QBLK;
    const int tid = (int)threadIdx.x;
    const int lane = tid & 63;
    const int w    = tid >> 6;   // wave 0..3
    const int c    = lane & 15;  // "column" lane index
    const int g    = lane >> 4;  // 4-lane-group index

    const size_t base = (size_t)bh * S_LEN * DH;
    const float* Qp = Qg + base;
    const float* Kp = Kg + base;
    const float* Vp = Vg + base;
    float*       Op = Og + base;

    const int qrow = q0 + w * QW;  // this wave's first q row

    // ---- Q fragments, held in registers for the whole kernel (scaled) ----
    // B-operand of 16x16x32: lane holds Q[qrow+qt*16+c][s*32 + 8g + j], j=0..7
    half8_t qf[2][2];
#pragma unroll
    for (int qt = 0; qt < 2; ++qt) {
        const float* qptr = Qp + (size_t)(qrow + qt * 16 + c) * DH;
#pragma unroll
        for (int s = 0; s < 2; ++s) {
            f32x4 a = *(const f32x4*)(qptr + s * 32 + g * 8);
            f32x4 b = *(const f32x4*)(qptr + s * 32 + g * 8 + 4);
            half8_t h;
#pragma unroll
            for (int j = 0; j < 4; ++j) {
                h[j]     = (_Float16)(a[j] * SCALE);
                h[j + 4] = (_Float16)(b[j] * SCALE);
            }
            qf[qt][s] = h;
        }
    }

    f32x4 oacc[4][2];   // O^T tiles: [dt][qt], d = 16*dt + 4g + r, q = qrow+16qt+c
#pragma unroll
    for (int dt = 0; dt < 4; ++dt)
#pragma unroll
        for (int qt = 0; qt < 2; ++qt)
            oacc[dt][qt] = (f32x4){0.f, 0.f, 0.f, 0.f};

    float m_run[2] = {-1e30f, -1e30f};
    float l_run[2] = {0.f, 0.f};

    const int wq_max = qrow + QW - 1;
    const int kv_end = q0 + QBLK;   // causal bound for this block (<= 2048)

    for (int kv0 = 0; kv0 < kv_end; kv0 += KVB) {
        __syncthreads();  // previous tile's LDS reads done before overwrite
        // ---- stage K (row-major) and V^T (transposed, scalar writes) ----
#pragma unroll
        for (int i = 0; i < 4; ++i) {
            int e  = tid + 256 * i;        // 0..1023
            int r  = e >> 4;               // kv row 0..63
            int c4 = (e & 15) << 2;        // d col 0,4,...,60
            const size_t goff = (size_t)(kv0 + r) * DH + c4;
            f32x4 kx = *(const f32x4*)(Kp + goff);
            half4_t kh;
#pragma unroll
            for (int j = 0; j < 4; ++j) kh[j] = (_Float16)kx[j];
            *(half4_t*)(Ks + swz_off(r, c4 * 2)) = kh;
            f32x4 vx = *(const f32x4*)(Vp + goff);
#pragma unroll
            for (int j = 0; j < 4; ++j)
                *(_Float16*)(Vs + swz_off(c4 + j, r * 2)) = (_Float16)vx[j];
        }
        __syncthreads();

        if (kv0 <= wq_max) {   // wave-uniform: skip fully-masked tiles
            // ---- QK^T (swapped): S^T[k][q] tiles [kt][qt] ----
            f32x4 st[4][2];
#pragma unroll
            for (int kt = 0; kt < 4; ++kt)
#pragma unroll
                for (int qt = 0; qt < 2; ++qt)
                    st[kt][qt] = (f32x4){0.f, 0.f, 0.f, 0.f};
#pragma unroll
            for (int kt = 0; kt < 4; ++kt) {
                // A-operand: K[kv0+16kt+c][s*32 + 8g + j]
                half8_t kf0 = *(const half8_t*)(Ks + swz_off(kt * 16 + c, g * 16));
                half8_t kf1 = *(const half8_t*)(Ks + swz_off(kt * 16 + c, 64 + g * 16));
#pragma unroll
                for (int qt = 0; qt < 2; ++qt) {
                    st[kt][qt] = __builtin_amdgcn_mfma_f32_16x16x32_f16(kf0, qf[qt][0], st[kt][qt], 0, 0, 0);
                    st[kt][qt] = __builtin_amdgcn_mfma_f32_16x16x32_f16(kf1, qf[qt][1], st[kt][qt], 0, 0, 0);
                }
            }
            // ---- causal mask (only tiles overlapping the diagonal) ----
            if (kv0 + KVB - 1 > qrow) {
#pragma unroll
                for (int qt = 0; qt < 2; ++qt) {
                    int qq = qrow + qt * 16 + c;
#pragma unroll
                    for (int kt = 0; kt < 4; ++kt)
#pragma unroll
                        for (int r = 0; r < 4; ++r) {
                            int kk = kv0 + kt * 16 + g * 4 + r;
                            if (kk > qq) st[kt][qt][r] = -1e30f;
                        }
                }
            }
            // ---- online softmax (in-register; reduce over g via 2 shuffles) ----
            half4_t pfq[2][4];   // P^T f16, directly in PV B-fragment layout
#pragma unroll
            for (int qt = 0; qt < 2; ++qt) {
                float tmax = -1e30f;
#pragma unroll
                for (int kt = 0; kt < 4; ++kt)
#pragma unroll
                    for (int r = 0; r < 4; ++r)
                        tmax = fmaxf(tmax, st[kt][qt][r]);
                tmax = fmaxf(tmax, __shfl_xor(tmax, 16));
                tmax = fmaxf(tmax, __shfl_xor(tmax, 32));
                float mnew  = fmaxf(m_run[qt], tmax);
                float alpha = __expf(m_run[qt] - mnew);
                m_run[qt] = mnew;
                float tsum = 0.f;
#pragma unroll
                for (int kt = 0; kt < 4; ++kt)
#pragma unroll
                    for (int r = 0; r < 4; ++r) {
                        float p = __expf(st[kt][qt][r] - mnew);
                        tsum += p;
                        pfq[qt][kt][r] = (_Float16)p;
                    }
                tsum += __shfl_xor(tsum, 16);
                tsum += __shfl_xor(tsum, 32);
                l_run[qt] = l_run[qt] * alpha + tsum;
#pragma unroll
                for (int dt = 0; dt < 4; ++dt)
                    oacc[dt][qt] = oacc[dt][qt] * alpha;
            }
            // ---- PV (swapped): O^T += V^T · P^T, 16x16x16 f16 ----
#pragma unroll
            for (int ks = 0; ks < 4; ++ks) {
                half4_t vf[4];
#pragma unroll
                for (int dt = 0; dt < 4; ++dt)  // A: V^T[16dt+c][16ks+4g+j]
                    vf[dt] = *(const half4_t*)(Vs + swz_off(dt * 16 + c, ks * 32 + g * 8));
#pragma unroll
                for (int qt = 0; qt < 2; ++qt)
#pragma unroll
                    for (int dt = 0; dt < 4; ++dt)
                        oacc[dt][qt] = __builtin_amdgcn_mfma_f32_16x16x16f16(vf[dt], pfq[qt][ks], oacc[dt][qt], 0, 0, 0);
            }
        }
    }

    // ---- epilogue: O[q][d] = acc / l, coalesced float4 stores ----
#pragma unroll
    for (int qt = 0; qt < 2; ++qt) {
        float inv = 1.f / l_run[qt];
        float* optr = Op + (size_t)(qrow + qt * 16 + c) * DH;
#pragma unroll
        for (int dt = 0; dt < 4; ++dt) {
            f32x4 o = oacc[dt][qt] * inv;
            *(f32x4*)(optr + dt * 16 + g * 4) = o;
        }
    }
}

extern "C" void kernel_launch(void* const* d_in, const int* in_sizes, int n_in,
                              void* d_out, int out_size, void* d_ws, size_t ws_size,
                              hipStream_t stream) {
    const float* Q = (const float*)d_in[0];
    const float* K = (const float*)d_in[1];
    const float* V = (const float*)d_in[2];
    float* O = (float*)d_out;
    dim3 grid(64, S_LEN / QBLK);   // (B*H, q-blocks); y reversed in-kernel
    fattn_kernel<<<grid, 256, 0, stream>>>(Q, K, V, O);
}

// Round 4
// 122.037 us; speedup vs baseline: 1.0235x; 1.0235x over previous
//
#include <hip/hip_runtime.h>

typedef _Float16 half2_t __attribute__((ext_vector_type(2)));
typedef _Float16 half4_t __attribute__((ext_vector_type(4)));
typedef _Float16 half8_t __attribute__((ext_vector_type(8)));
typedef float    f32x4   __attribute__((ext_vector_type(4)));

#define S_LEN 2048
#define DH    64
#define QBLK  64    // q rows per block (4 waves x 16)
#define KVB   64    // kv rows per tile
// (1/sqrt(1024)) * log2(e): softmax done in exp2 domain
#define SCALE 0.045110910340389066f

// XOR-swizzle for [row][128B] LDS tiles. Key bits 4..6 (+bit 3 below)
// spread the stride-128B column-slice reads across banks (m214 r268).
__device__ __forceinline__ int swz_off(int row, int byteInRow) {
    return row * 128 + (byteInRow ^ ((row & 7) << 4));
}
// V^T tile swizzle: extra bit-3 key keeps 8B-aligned atoms and puts both
// the b64 writes and b64 reads at the width floor (4-way).
__device__ __forceinline__ int vswz(int row, int byteInRow) {
    return row * 128 + (byteInRow ^ ((row & 7) << 4) ^ (row & 8));
}

__device__ __forceinline__ half4_t cvt4(f32x4 x) {
    half2_t a = __builtin_bit_cast(half2_t, __builtin_amdgcn_cvt_pkrtz(x[0], x[1]));
    half2_t b = __builtin_bit_cast(half2_t, __builtin_amdgcn_cvt_pkrtz(x[2], x[3]));
    half4_t r; r[0] = a[0]; r[1] = a[1]; r[2] = b[0]; r[3] = b[1];
    return r;
}

__global__ __launch_bounds__(256, 8)
void fattn_kernel(const float* __restrict__ Qg, const float* __restrict__ Kg,
                  const float* __restrict__ Vg, float* __restrict__ Og) {
    __shared__ __align__(16) char smem[16384];
    char* const Ks = smem;          // K tile  [64 k][64 d] f16, swizzled
    char* const Vs = smem + 8192;   // V^T tile [64 d][64 k] f16, vswz

    const int bh  = (int)blockIdx.x;                 // 0..63
    const int qb  = 31 - (int)blockIdx.y;            // heavy blocks first
    const int q0  = qb * QBLK;
    const int tid = (int)threadIdx.x;
    const int lane = tid & 63;
    const int w    = tid >> 6;
    const int c    = lane & 15;
    const int g    = lane >> 4;

    const size_t base = (size_t)bh * S_LEN * DH;
    const float* Qp = Qg + base;
    const float* Kp = Kg + base;
    const float* Vp = Vg + base;
    float*       Op = Og + base;

    const int qrow = q0 + w * 16;   // wave's 16 q rows

    // ---- staging index precompute ----
    const int r0  = tid >> 4;            // K row 0..15 (+16 per i)
    const int c4  = (tid & 15) << 2;     // K f32 col
    const int kLds0  = swz_off(r0, c4 * 2);            // +i*2048
    const int kGlob0 = r0 * DH + c4;                   // +kv0*64 + i*1024
    const int kq4 = (tid >> 4) << 2;     // V k-quad base 0..60
    const int d4  = (tid & 15) << 2;     // V d-quad base 0..60

    // ---- Q fragments in registers (scaled into exp2 domain) ----
    half8_t qf0, qf1;
    {
        const float* qptr = Qp + (size_t)(qrow + c) * DH;
#pragma unroll
        for (int s = 0; s < 2; ++s) {
            f32x4 a = *(const f32x4*)(qptr + s * 32 + g * 8);
            f32x4 b = *(const f32x4*)(qptr + s * 32 + g * 8 + 4);
            half8_t h;
#pragma unroll
            for (int j = 0; j < 4; ++j) {
                h[j]     = (_Float16)(a[j] * SCALE);
                h[j + 4] = (_Float16)(b[j] * SCALE);
            }
            if (s == 0) qf0 = h; else qf1 = h;
        }
    }

    f32x4 oacc[4];   // O^T: d = 16*dt + 4g + r, q = qrow + c
#pragma unroll
    for (int dt = 0; dt < 4; ++dt) oacc[dt] = (f32x4){0.f, 0.f, 0.f, 0.f};
    float m_run = -1e30f, l_run = 0.f;

    const int nT = q0 / KVB + 1;   // causal tile count for this block

    for (int t = 0; t < nT; ++t) {
        const int kv0 = t * KVB;
        __syncthreads();  // previous tile's LDS reads done before overwrite
        // ---- stage K (swizzled row-major), vectorized ----
#pragma unroll
        for (int i = 0; i < 4; ++i) {
            f32x4 kx = *(const f32x4*)(Kp + (size_t)(kv0 * DH + kGlob0 + i * 1024));
            *(half4_t*)(Ks + kLds0 + i * 2048) = cvt4(kx);
        }
        // ---- stage V^T via 4x4 register transpose, vectorized writes ----
        {
            f32x4 vr[4];
#pragma unroll
            for (int j = 0; j < 4; ++j)
                vr[j] = *(const f32x4*)(Vp + (size_t)((kv0 + kq4 + j) * DH + d4));
#pragma unroll
            for (int jj = 0; jj < 4; ++jj) {
                f32x4 tcol = (f32x4){vr[0][jj], vr[1][jj], vr[2][jj], vr[3][jj]};
                *(half4_t*)(Vs + vswz(d4 + jj, kq4 * 2)) = cvt4(tcol);
            }
        }
        __syncthreads();

        // ---- QK^T swapped: S^T[k][q], k = kv0+16kt+4g+r, q = qrow+c ----
        f32x4 st[4];
#pragma unroll
        for (int kt = 0; kt < 4; ++kt) st[kt] = (f32x4){0.f, 0.f, 0.f, 0.f};
#pragma unroll
        for (int kt = 0; kt < 4; ++kt) {
            half8_t kf0 = *(const half8_t*)(Ks + swz_off(kt * 16 + c, g * 16));
            half8_t kf1 = *(const half8_t*)(Ks + swz_off(kt * 16 + c, 64 + g * 16));
            st[kt] = __builtin_amdgcn_mfma_f32_16x16x32_f16(kf0, qf0, st[kt], 0, 0, 0);
            st[kt] = __builtin_amdgcn_mfma_f32_16x16x32_f16(kf1, qf1, st[kt], 0, 0, 0);
        }

        // ---- causal mask: only the diagonal (last) tile needs it ----
        if (t == nT - 1) {
            const int qq = qrow + c;
#pragma unroll
            for (int kt = 0; kt < 4; ++kt)
#pragma unroll
                for (int r = 0; r < 4; ++r)
                    if (kv0 + kt * 16 + g * 4 + r > qq) st[kt][r] = -1e30f;
        }

        // ---- online softmax (exp2 domain), in-register ----
        float tmax = -1e30f;
#pragma unroll
        for (int kt = 0; kt < 4; ++kt)
#pragma unroll
            for (int r = 0; r < 4; ++r) tmax = fmaxf(tmax, st[kt][r]);
        tmax = fmaxf(tmax, __shfl_xor(tmax, 16));
        tmax = fmaxf(tmax, __shfl_xor(tmax, 32));
        const float mnew  = fmaxf(m_run, tmax);
        const float alpha = exp2f(m_run - mnew);
        m_run = mnew;
        float tsum = 0.f;
        half4_t pfq[4];   // P^T f16, already in PV B-fragment layout
#pragma unroll
        for (int kt = 0; kt < 4; ++kt) {
#pragma unroll
            for (int r = 0; r < 4; ++r) {
                float p = exp2f(st[kt][r] - mnew);
                tsum += p;
                st[kt][r] = p;
            }
            pfq[kt] = cvt4(st[kt]);
        }
        tsum += __shfl_xor(tsum, 16);
        tsum += __shfl_xor(tsum, 32);
        l_run = l_run * alpha + tsum;
#pragma unroll
        for (int dt = 0; dt < 4; ++dt) oacc[dt] = oacc[dt] * alpha;

        // ---- PV: O^T += V^T . P^T via 16x16x16 f16 ----
#pragma unroll
        for (int ks = 0; ks < 4; ++ks) {
            half4_t vf[4];
#pragma unroll
            for (int dt = 0; dt < 4; ++dt)  // A: V^T[16dt+c][16ks+4g+j]
                vf[dt] = *(const half4_t*)(Vs + vswz(dt * 16 + c, ks * 32 + g * 8));
#pragma unroll
            for (int dt = 0; dt < 4; ++dt)
                oacc[dt] = __builtin_amdgcn_mfma_f32_16x16x16f16(vf[dt], pfq[ks], oacc[dt], 0, 0, 0);
        }
    }

    // ---- epilogue ----
    const float inv = __builtin_amdgcn_rcpf(l_run);
    float* optr = Op + (size_t)(qrow + c) * DH;
#pragma unroll
    for (int dt = 0; dt < 4; ++dt) {
        f32x4 o = oacc[dt] * inv;
        *(f32x4*)(optr + dt * 16 + g * 4) = o;
    }
}

extern "C" void kernel_launch(void* const* d_in, const int* in_sizes, int n_in,
                              void* d_out, int out_size, void* d_ws, size_t ws_size,
                              hipStream_t stream) {
    (void)in_sizes; (void)n_in; (void)out_size; (void)d_ws; (void)ws_size;
    const float* Q = (const float*)d_in[0];
    const float* K = (const float*)d_in[1];
    const float* V = (const float*)d_in[2];
    float* O = (float*)d_out;
    dim3 grid(64, S_LEN / QBLK);
    fattn_kernel<<<grid, 256, 0, stream>>>(Q, K, V, O);
}

// Round 5
// 89.015 us; speedup vs baseline: 1.4033x; 1.3710x over previous
//
#include <hip/hip_runtime.h>

typedef _Float16 half2_t __attribute__((ext_vector_type(2)));
typedef _Float16 half4_t __attribute__((ext_vector_type(4)));
typedef _Float16 half8_t __attribute__((ext_vector_type(8)));
typedef float    f32x4   __attribute__((ext_vector_type(4)));

#define S_LEN 2048
#define DH    64
#define QBLK  64    // q rows per block (4 waves x 16)
#define KVB   64    // kv rows per tile
// (1/sqrt(1024)) * log2(e): softmax done in exp2 domain
#define SCALE 0.045110910340389066f
#define DEFER_THR 8.0f   // T13: skip rescale while tile max within 2^8 of running max

// XOR-swizzle for [row][128B] LDS tiles (m214 r268).
__device__ __forceinline__ int swz_off(int row, int byteInRow) {
    return row * 128 + (byteInRow ^ ((row & 7) << 4));
}
// V^T tile swizzle: extra bit-3 key -> both b64 writes and b64 reads at width floor.
__device__ __forceinline__ int vswz(int row, int byteInRow) {
    return row * 128 + (byteInRow ^ ((row & 7) << 4) ^ (row & 8));
}

__device__ __forceinline__ half4_t cvt4(f32x4 x) {
    half2_t a = __builtin_bit_cast(half2_t, __builtin_amdgcn_cvt_pkrtz(x[0], x[1]));
    half2_t b = __builtin_bit_cast(half2_t, __builtin_amdgcn_cvt_pkrtz(x[2], x[3]));
    half4_t r; r[0] = a[0]; r[1] = a[1]; r[2] = b[0]; r[3] = b[1];
    return r;
}

__global__ __launch_bounds__(256, 4)
void fattn_kernel(const float* __restrict__ Qg, const float* __restrict__ Kg,
                  const float* __restrict__ Vg, float* __restrict__ Og) {
    __shared__ __align__(16) char smem[16384];
    char* const Ks = smem;          // K tile  [64 k][64 d] f16, swizzled
    char* const Vs = smem + 8192;   // V^T tile [64 d][64 k] f16, vswz

    const int bh  = (int)blockIdx.x;                 // 0..63
    const int qb  = 31 - (int)blockIdx.y;            // heavy blocks first
    const int q0  = qb * QBLK;
    const int tid = (int)threadIdx.x;
    const int lane = tid & 63;
    const int w    = tid >> 6;
    const int c    = lane & 15;
    const int g    = lane >> 4;

    const size_t base = (size_t)bh * S_LEN * DH;
    const float* Qp = Qg + base;
    const float* Kp = Kg + base;
    const float* Vp = Vg + base;
    float*       Op = Og + base;

    const int qrow = q0 + w * 16;   // wave's 16 q rows

    // ---- staging index precompute ----
    const int r0  = tid >> 4;            // K row 0..15 (+16 per i)
    const int c4  = (tid & 15) << 2;     // K f32 col
    const int kLds0  = swz_off(r0, c4 * 2);            // +i*2048
    const int kGlob0 = r0 * DH + c4;                   // +kv0*64 + i*1024
    const int kq4 = (tid >> 4) << 2;     // V k-quad base 0..60
    const int d4  = (tid & 15) << 2;     // V d-quad base 0..60

    // ---- Q fragments in registers (scaled into exp2 domain) ----
    half8_t qf0, qf1;
    {
        const float* qptr = Qp + (size_t)(qrow + c) * DH;
#pragma unroll
        for (int s = 0; s < 2; ++s) {
            f32x4 a = *(const f32x4*)(qptr + s * 32 + g * 8);
            f32x4 b = *(const f32x4*)(qptr + s * 32 + g * 8 + 4);
            half8_t h;
#pragma unroll
            for (int j = 0; j < 4; ++j) {
                h[j]     = (_Float16)(a[j] * SCALE);
                h[j + 4] = (_Float16)(b[j] * SCALE);
            }
            if (s == 0) qf0 = h; else qf1 = h;
        }
    }

    f32x4 oacc[4];   // O^T: d = 16*dt + 4g + r, q = qrow + c
#pragma unroll
    for (int dt = 0; dt < 4; ++dt) oacc[dt] = (f32x4){0.f, 0.f, 0.f, 0.f};
    float m_run = -1e30f, l_run = 0.f;

    const int nT = q0 / KVB + 1;   // causal tile count for this block

    for (int t = 0; t < nT; ++t) {
        const int kv0 = t * KVB;
        __syncthreads();  // previous tile's LDS reads done before overwrite
        // ---- stage K (swizzled row-major), vectorized ----
#pragma unroll
        for (int i = 0; i < 4; ++i) {
            f32x4 kx = *(const f32x4*)(Kp + (size_t)(kv0 * DH + kGlob0 + i * 1024));
            *(half4_t*)(Ks + kLds0 + i * 2048) = cvt4(kx);
        }
        // ---- stage V^T via 4x4 register transpose, vectorized writes ----
        {
            f32x4 vr[4];
#pragma unroll
            for (int j = 0; j < 4; ++j)
                vr[j] = *(const f32x4*)(Vp + (size_t)((kv0 + kq4 + j) * DH + d4));
#pragma unroll
            for (int jj = 0; jj < 4; ++jj) {
                f32x4 tcol = (f32x4){vr[0][jj], vr[1][jj], vr[2][jj], vr[3][jj]};
                *(half4_t*)(Vs + vswz(d4 + jj, kq4 * 2)) = cvt4(tcol);
            }
        }
        __syncthreads();

        // ---- QK^T swapped: S^T[k][q], k = kv0+16kt+4g+r, q = qrow+c ----
        f32x4 st[4];
#pragma unroll
        for (int kt = 0; kt < 4; ++kt) st[kt] = (f32x4){0.f, 0.f, 0.f, 0.f};
#pragma unroll
        for (int kt = 0; kt < 4; ++kt) {
            half8_t kf0 = *(const half8_t*)(Ks + swz_off(kt * 16 + c, g * 16));
            half8_t kf1 = *(const half8_t*)(Ks + swz_off(kt * 16 + c, 64 + g * 16));
            st[kt] = __builtin_amdgcn_mfma_f32_16x16x32_f16(kf0, qf0, st[kt], 0, 0, 0);
            st[kt] = __builtin_amdgcn_mfma_f32_16x16x32_f16(kf1, qf1, st[kt], 0, 0, 0);
        }

        // ---- causal mask: only the diagonal (last) tile needs it ----
        if (t == nT - 1) {
            const int qq = qrow + c;
#pragma unroll
            for (int kt = 0; kt < 4; ++kt)
#pragma unroll
                for (int r = 0; r < 4; ++r)
                    if (kv0 + kt * 16 + g * 4 + r > qq) st[kt][r] = -1e30f;
        }

        // ---- online softmax (exp2 domain), in-register, T13 defer-max ----
        float tmax = -1e30f;
#pragma unroll
        for (int kt = 0; kt < 4; ++kt)
#pragma unroll
            for (int r = 0; r < 4; ++r) tmax = fmaxf(tmax, st[kt][r]);
        tmax = fmaxf(tmax, __shfl_xor(tmax, 16));
        tmax = fmaxf(tmax, __shfl_xor(tmax, 32));
        if (!__all(tmax - m_run <= DEFER_THR)) {
            const float mnew  = fmaxf(m_run, tmax);
            const float alpha = exp2f(m_run - mnew);
            m_run = mnew;
            l_run *= alpha;
#pragma unroll
            for (int dt = 0; dt < 4; ++dt) oacc[dt] = oacc[dt] * alpha;
        }
        float tsum = 0.f;
        half4_t pfq[4];   // P^T f16, already in PV B-fragment layout
#pragma unroll
        for (int kt = 0; kt < 4; ++kt) {
#pragma unroll
            for (int r = 0; r < 4; ++r) {
                float p = exp2f(st[kt][r] - m_run);
                tsum += p;
                st[kt][r] = p;
            }
            pfq[kt] = cvt4(st[kt]);
        }
        tsum += __shfl_xor(tsum, 16);
        tsum += __shfl_xor(tsum, 32);
        l_run += tsum;

        // ---- PV: O^T += V^T . P^T via 16x16x16 f16 ----
#pragma unroll
        for (int ks = 0; ks < 4; ++ks) {
            half4_t vf[4];
#pragma unroll
            for (int dt = 0; dt < 4; ++dt)  // A: V^T[16dt+c][16ks+4g+j]
                vf[dt] = *(const half4_t*)(Vs + vswz(dt * 16 + c, ks * 32 + g * 8));
#pragma unroll
            for (int dt = 0; dt < 4; ++dt)
                oacc[dt] = __builtin_amdgcn_mfma_f32_16x16x16f16(vf[dt], pfq[ks], oacc[dt], 0, 0, 0);
        }
    }

    // ---- epilogue ----
    const float inv = __builtin_amdgcn_rcpf(l_run);
    float* optr = Op + (size_t)(qrow + c) * DH;
#pragma unroll
    for (int dt = 0; dt < 4; ++dt) {
        f32x4 o = oacc[dt] * inv;
        *(f32x4*)(optr + dt * 16 + g * 4) = o;
    }
}

extern "C" void kernel_launch(void* const* d_in, const int* in_sizes, int n_in,
                              void* d_out, int out_size, void* d_ws, size_t ws_size,
                              hipStream_t stream) {
    (void)in_sizes; (void)n_in; (void)out_size; (void)d_ws; (void)ws_size;
    const float* Q = (const float*)d_in[0];
    const float* K = (const float*)d_in[1];
    const float* V = (const float*)d_in[2];
    float* O = (float*)d_out;
    dim3 grid(64, S_LEN / QBLK);
    fattn_kernel<<<grid, 256, 0, stream>>>(Q, K, V, O);
}

// Round 6
// 82.974 us; speedup vs baseline: 1.5054x; 1.0728x over previous
//
#include <hip/hip_runtime.h>

typedef _Float16 half2_t __attribute__((ext_vector_type(2)));
typedef _Float16 half4_t __attribute__((ext_vector_type(4)));
typedef _Float16 half8_t __attribute__((ext_vector_type(8)));
typedef float    f32x4   __attribute__((ext_vector_type(4)));

#define S_LEN 2048
#define DH    64
#define QBLK  64    // q rows per block (4 waves x 16)
#define KVB   64    // kv rows per tile
// (1/sqrt(1024)) * log2(e): softmax in exp2 domain
#define SCALE 0.045110910340389066f
#define DEFER_THR 8.0f   // T13: P bounded by 2^8, f16-safe

// XOR-swizzle for [row][128B] LDS tiles (m214 r268).
__device__ __forceinline__ int swz_off(int row, int byteInRow) {
    return row * 128 + (byteInRow ^ ((row & 7) << 4));
}
// V^T tile swizzle: extra bit-3 key -> b64 writes and reads at width floor.
__device__ __forceinline__ int vswz(int row, int byteInRow) {
    return row * 128 + (byteInRow ^ ((row & 7) << 4) ^ (row & 8));
}

__device__ __forceinline__ half4_t cvt4(f32x4 x) {
    half2_t a = __builtin_bit_cast(half2_t, __builtin_amdgcn_cvt_pkrtz(x[0], x[1]));
    half2_t b = __builtin_bit_cast(half2_t, __builtin_amdgcn_cvt_pkrtz(x[2], x[3]));
    half4_t r; r[0] = a[0]; r[1] = a[1]; r[2] = b[0]; r[3] = b[1];
    return r;
}

__global__ __launch_bounds__(256, 4)
void fattn_kernel(const float* __restrict__ Qg, const float* __restrict__ Kg,
                  const float* __restrict__ Vg, float* __restrict__ Og) {
    __shared__ __align__(16) char smem[32768];   // 2 x (K 8KB + V^T 8KB)

    const int bh  = (int)blockIdx.x;                 // 0..63
    const int qb  = 31 - (int)blockIdx.y;            // heavy blocks first
    const int q0  = qb * QBLK;
    const int tid = (int)threadIdx.x;
    const int lane = tid & 63;
    const int w    = tid >> 6;
    const int c    = lane & 15;
    const int g    = lane >> 4;

    const size_t base = (size_t)bh * S_LEN * DH;
    const float* Qp = Qg + base;
    const float* Kp = Kg + base;
    const float* Vp = Vg + base;
    float*       Op = Og + base;

    const int qrow = q0 + w * 16;   // wave's 16 q rows

    // staging index precompute
    const int r0  = tid >> 4;             // K row 0..15 (+16 per i)
    const int c4  = (tid & 15) << 2;      // K f32 col
    const int kLds0  = swz_off(r0, c4 * 2);   // +i*2048
    const int kGlob0 = r0 * DH + c4;          // +kv*64 + i*1024
    const int kq4 = (tid >> 4) << 2;      // V k-quad 0..60
    const int d4  = (tid & 15) << 2;      // V d-quad 0..60

    // ---- Q fragments in registers (scaled into exp2 domain) ----
    half8_t qf0, qf1;
    {
        const float* qptr = Qp + (size_t)(qrow + c) * DH;
#pragma unroll
        for (int s = 0; s < 2; ++s) {
            f32x4 a = *(const f32x4*)(qptr + s * 32 + g * 8);
            f32x4 b = *(const f32x4*)(qptr + s * 32 + g * 8 + 4);
            half8_t h;
#pragma unroll
            for (int j = 0; j < 4; ++j) {
                h[j]     = (_Float16)(a[j] * SCALE);
                h[j + 4] = (_Float16)(b[j] * SCALE);
            }
            if (s == 0) qf0 = h; else qf1 = h;
        }
    }

    f32x4 oacc[4];   // O^T: d = 16*dt + 4g + r, q = qrow + c
#pragma unroll
    for (int dt = 0; dt < 4; ++dt) oacc[dt] = (f32x4){0.f, 0.f, 0.f, 0.f};
    float m_run = -1e30f;
    float l_run = 0.f;            // PER-LANE partial; reduced once at the end

    const int nT = q0 / KVB + 1;

    // ---- prologue: stage tile 0 into buffer 0 ----
    f32x4 kr[4], vr[4];
#pragma unroll
    for (int i = 0; i < 4; ++i)
        kr[i] = *(const f32x4*)(Kp + (size_t)(kGlob0 + i * 1024));
#pragma unroll
    for (int j = 0; j < 4; ++j)
        vr[j] = *(const f32x4*)(Vp + (size_t)((kq4 + j) * DH + d4));
    {
        char* const Kw = smem;
        char* const Vw = smem + 8192;
#pragma unroll
        for (int i = 0; i < 4; ++i)
            *(half4_t*)(Kw + kLds0 + i * 2048) = cvt4(kr[i]);
#pragma unroll
        for (int jj = 0; jj < 4; ++jj) {   // column pack: zero-cost subreg operands
            half2_t lo = __builtin_bit_cast(half2_t, __builtin_amdgcn_cvt_pkrtz(vr[0][jj], vr[1][jj]));
            half2_t hi = __builtin_bit_cast(half2_t, __builtin_amdgcn_cvt_pkrtz(vr[2][jj], vr[3][jj]));
            half4_t col; col[0] = lo[0]; col[1] = lo[1]; col[2] = hi[0]; col[3] = hi[1];
            *(half4_t*)(Vw + vswz(d4 + jj, kq4 * 2)) = col;
        }
    }

    int cur = 0;
    for (int t = 0; t < nT; ++t) {
        __syncthreads();   // buf[cur] fully written; prior reads of buf[cur] done
        const bool pf = (t + 1 < nT);
        if (pf) {          // issue-early: loads overlap this tile's compute
            const int kv1 = (t + 1) * KVB;
#pragma unroll
            for (int i = 0; i < 4; ++i)
                kr[i] = *(const f32x4*)(Kp + (size_t)(kv1 * DH + kGlob0 + i * 1024));
#pragma unroll
            for (int j = 0; j < 4; ++j)
                vr[j] = *(const f32x4*)(Vp + (size_t)((kv1 + kq4 + j) * DH + d4));
        }
        char* const Ks = smem + cur * 16384;
        char* const Vs = Ks + 8192;

        // ---- QK^T swapped: S^T[k][q], k = kv0+16kt+4g+r, q = qrow+c ----
        f32x4 st[4];
#pragma unroll
        for (int kt = 0; kt < 4; ++kt) st[kt] = (f32x4){0.f, 0.f, 0.f, 0.f};
        __builtin_amdgcn_s_setprio(1);
#pragma unroll
        for (int kt = 0; kt < 4; ++kt) {
            half8_t kf0 = *(const half8_t*)(Ks + swz_off(kt * 16 + c, g * 16));
            half8_t kf1 = *(const half8_t*)(Ks + swz_off(kt * 16 + c, 64 + g * 16));
            st[kt] = __builtin_amdgcn_mfma_f32_16x16x32_f16(kf0, qf0, st[kt], 0, 0, 0);
            st[kt] = __builtin_amdgcn_mfma_f32_16x16x32_f16(kf1, qf1, st[kt], 0, 0, 0);
        }
        __builtin_amdgcn_s_setprio(0);

        // ---- causal mask: only the diagonal tile ----
        if (t == nT - 1) {
            const int kv0 = t * KVB;
            const int qq = qrow + c;
#pragma unroll
            for (int kt = 0; kt < 4; ++kt)
#pragma unroll
                for (int r = 0; r < 4; ++r)
                    if (kv0 + kt * 16 + g * 4 + r > qq) st[kt][r] = -1e30f;
        }

        // ---- online softmax (exp2 domain), tree max, deferred l-reduce ----
        float a0 = fmaxf(fmaxf(st[0][0], st[0][1]), fmaxf(st[0][2], st[0][3]));
        float a1 = fmaxf(fmaxf(st[1][0], st[1][1]), fmaxf(st[1][2], st[1][3]));
        float a2 = fmaxf(fmaxf(st[2][0], st[2][1]), fmaxf(st[2][2], st[2][3]));
        float a3 = fmaxf(fmaxf(st[3][0], st[3][1]), fmaxf(st[3][2], st[3][3]));
        float tmax = fmaxf(fmaxf(a0, a1), fmaxf(a2, a3));
        tmax = fmaxf(tmax, __shfl_xor(tmax, 16));
        tmax = fmaxf(tmax, __shfl_xor(tmax, 32));
        if (!__all(tmax - m_run <= DEFER_THR)) {
            const float mnew  = fmaxf(m_run, tmax);
            const float alpha = __builtin_amdgcn_exp2f(m_run - mnew);
            m_run = mnew;
            l_run *= alpha;
#pragma unroll
            for (int dt = 0; dt < 4; ++dt) oacc[dt] = oacc[dt] * alpha;
        }
        float tsum = 0.f;
        half4_t pfq[4];   // P^T f16, already in PV B-fragment layout
#pragma unroll
        for (int kt = 0; kt < 4; ++kt) {
#pragma unroll
            for (int r = 0; r < 4; ++r) {
                float p = __builtin_amdgcn_exp2f(st[kt][r] - m_run);
                tsum += p;
                st[kt][r] = p;
            }
            pfq[kt] = cvt4(st[kt]);
        }
        l_run += tsum;    // per-lane partial; no per-tile shuffles

        // ---- PV: O^T += V^T . P^T via 16x16x16 f16 ----
        __builtin_amdgcn_s_setprio(1);
#pragma unroll
        for (int ks = 0; ks < 4; ++ks) {
            half4_t vf[4];
#pragma unroll
            for (int dt = 0; dt < 4; ++dt)  // A: V^T[16dt+c][16ks+4g+j]
                vf[dt] = *(const half4_t*)(Vs + vswz(dt * 16 + c, ks * 32 + g * 8));
#pragma unroll
            for (int dt = 0; dt < 4; ++dt)
                oacc[dt] = __builtin_amdgcn_mfma_f32_16x16x16f16(vf[dt], pfq[ks], oacc[dt], 0, 0, 0);
        }
        __builtin_amdgcn_s_setprio(0);

        // ---- write-late: stage t+1 into the other buffer ----
        if (pf) {
            char* const Kw = smem + (cur ^ 1) * 16384;
            char* const Vw = Kw + 8192;
#pragma unroll
            for (int i = 0; i < 4; ++i)
                *(half4_t*)(Kw + kLds0 + i * 2048) = cvt4(kr[i]);
#pragma unroll
            for (int jj = 0; jj < 4; ++jj) {
                half2_t lo = __builtin_bit_cast(half2_t, __builtin_amdgcn_cvt_pkrtz(vr[0][jj], vr[1][jj]));
                half2_t hi = __builtin_bit_cast(half2_t, __builtin_amdgcn_cvt_pkrtz(vr[2][jj], vr[3][jj]));
                half4_t col; col[0] = lo[0]; col[1] = lo[1]; col[2] = hi[0]; col[3] = hi[1];
                *(half4_t*)(Vw + vswz(d4 + jj, kq4 * 2)) = col;
            }
        }
        cur ^= 1;
    }

    // ---- epilogue: reduce l across the 4 g-groups, normalize, store ----
    l_run += __shfl_xor(l_run, 16);
    l_run += __shfl_xor(l_run, 32);
    const float inv = __builtin_amdgcn_rcpf(l_run);
    float* optr = Op + (size_t)(qrow + c) * DH;
#pragma unroll
    for (int dt = 0; dt < 4; ++dt) {
        f32x4 o = oacc[dt] * inv;
        *(f32x4*)(optr + dt * 16 + g * 4) = o;
    }
}

extern "C" void kernel_launch(void* const* d_in, const int* in_sizes, int n_in,
                              void* d_out, int out_size, void* d_ws, size_t ws_size,
                              hipStream_t stream) {
    (void)in_sizes; (void)n_in; (void)out_size; (void)d_ws; (void)ws_size;
    const float* Q = (const float*)d_in[0];
    const float* K = (const float*)d_in[1];
    const float* V = (const float*)d_in[2];
    float* O = (float*)d_out;
    dim3 grid(64, S_LEN / QBLK);
    fattn_kernel<<<grid, 256, 0, stream>>>(Q, K, V, O);
}

// Round 7
// 74.938 us; speedup vs baseline: 1.6669x; 1.1072x over previous
//
#include <hip/hip_runtime.h>

typedef _Float16 half2_t __attribute__((ext_vector_type(2)));
typedef _Float16 half4_t __attribute__((ext_vector_type(4)));
typedef _Float16 half8_t __attribute__((ext_vector_type(8)));
typedef float    f32x4   __attribute__((ext_vector_type(4)));

#define S_LEN 2048
#define DH    64
#define QBLK  128   // q rows per block (8 waves x 16)
#define KVB   64    // kv rows per tile
#define NQB   16    // q-blocks total; block handles pair (pb, 15-pb) -> 34 tiles each
// (1/sqrt(1024)) * log2(e): softmax in exp2 domain
#define SCALE 0.045110910340389066f
#define DEFER_THR 8.0f   // T13: P bounded by 2^8, f16-safe

// XOR-swizzle for [row][128B] LDS tiles (m214 r268).
__device__ __forceinline__ int swz_off(int row, int byteInRow) {
    return row * 128 + (byteInRow ^ ((row & 7) << 4));
}
// V^T tile swizzle: extra bit-3 key -> b64 writes and reads at width floor.
__device__ __forceinline__ int vswz(int row, int byteInRow) {
    return row * 128 + (byteInRow ^ ((row & 7) << 4) ^ (row & 8));
}

__device__ __forceinline__ half4_t cvt4(f32x4 x) {
    half2_t a = __builtin_bit_cast(half2_t, __builtin_amdgcn_cvt_pkrtz(x[0], x[1]));
    half2_t b = __builtin_bit_cast(half2_t, __builtin_amdgcn_cvt_pkrtz(x[2], x[3]));
    half4_t r; r[0] = a[0]; r[1] = a[1]; r[2] = b[0]; r[3] = b[1];
    return r;
}
__device__ __forceinline__ float fmax3(float a, float b, float c) {
    return fmaxf(fmaxf(a, b), c);   // fuses to v_max3_f32
}

__global__ __launch_bounds__(512, 4)
void fattn_kernel(const float* __restrict__ Qg, const float* __restrict__ Kg,
                  const float* __restrict__ Vg, float* __restrict__ Og) {
    __shared__ __align__(16) char smem[32768];   // 2 x (K 8KB + V^T 8KB)

    const int bh  = (int)blockIdx.x;     // 0..63
    const int pb  = (int)blockIdx.y;     // 0..7 -> q-block pair (pb, 15-pb)
    const int tid = (int)threadIdx.x;
    const int lane = tid & 63;
    const int w    = tid >> 6;           // wave 0..7
    const int c    = lane & 15;
    const int g    = lane >> 4;

    const size_t base = (size_t)bh * S_LEN * DH;
    const float* Qp = Qg + base;
    const float* Kp = Kg + base;
    const float* Vp = Vg + base;
    float*       Op = Og + base;

    // ---- staging task split: waves 0-3 stage K, waves 4-7 stage V ----
    const bool isK = tid < 256;
    const int sid = tid & 255;
    const int r0  = sid >> 4;            // K row 0..15 (+16 per i)
    const int c4  = (sid & 15) << 2;     // K f32 col
    const int kLds0 = swz_off(r0, c4 * 2);   // +i*2048
    const int kq4 = (sid >> 4) << 2;     // V k-quad 0..60
    const int d4  = (sid & 15) << 2;     // V d-quad 0..60

    for (int phase = 0; phase < 2; ++phase) {
        const int qb = phase ? (NQB - 1 - pb) : pb;
        const int q0 = qb * QBLK;
        const int qrow = q0 + w * 16;    // wave's 16 q rows
        const int nT = 2 * qb + 2;       // kv tiles for this q-block

        if (phase) __syncthreads();      // phase-A readers done before reuse

        // ---- Q fragments (scaled into exp2 domain) ----
        half8_t qf0, qf1;
        {
            const float* qptr = Qp + (size_t)(qrow + c) * DH;
#pragma unroll
            for (int s = 0; s < 2; ++s) {
                f32x4 a = *(const f32x4*)(qptr + s * 32 + g * 8);
                f32x4 b = *(const f32x4*)(qptr + s * 32 + g * 8 + 4);
                half8_t h;
#pragma unroll
                for (int j = 0; j < 4; ++j) {
                    h[j]     = (_Float16)(a[j] * SCALE);
                    h[j + 4] = (_Float16)(b[j] * SCALE);
                }
                if (s == 0) qf0 = h; else qf1 = h;
            }
        }

        f32x4 oacc[4];
#pragma unroll
        for (int dt = 0; dt < 4; ++dt) oacc[dt] = (f32x4){0.f, 0.f, 0.f, 0.f};
        float m_run = -1e30f, l_run = 0.f;

        // ---- staging helpers (role-specific, 4 regs) ----
        f32x4 pr[4];
        auto stage_load = [&](int kv) {
            if (isK) {
#pragma unroll
                for (int i = 0; i < 4; ++i)
                    pr[i] = *(const f32x4*)(Kp + (size_t)((kv + r0 + 16 * i) * DH + c4));
            } else {
#pragma unroll
                for (int j = 0; j < 4; ++j)
                    pr[j] = *(const f32x4*)(Vp + (size_t)((kv + kq4 + j) * DH + d4));
            }
        };
        auto stage_write = [&](char* buf) {
            if (isK) {
#pragma unroll
                for (int i = 0; i < 4; ++i)
                    *(half4_t*)(buf + kLds0 + i * 2048) = cvt4(pr[i]);
            } else {
                char* Vw = buf + 8192;
#pragma unroll
                for (int jj = 0; jj < 4; ++jj) {   // column pack: subreg operands
                    half2_t lo = __builtin_bit_cast(half2_t, __builtin_amdgcn_cvt_pkrtz(pr[0][jj], pr[1][jj]));
                    half2_t hi = __builtin_bit_cast(half2_t, __builtin_amdgcn_cvt_pkrtz(pr[2][jj], pr[3][jj]));
                    half4_t col; col[0] = lo[0]; col[1] = lo[1]; col[2] = hi[0]; col[3] = hi[1];
                    *(half4_t*)(Vw + vswz(d4 + jj, kq4 * 2)) = col;
                }
            }
        };

        // ---- prologue: stage tile 0 into buffer 0 ----
        stage_load(0);
        stage_write(smem);

        int cur = 0;
        for (int t = 0; t < nT; ++t) {
            __syncthreads();   // buf[cur] written; prior reads of buf[cur^1] done
            const bool pf = (t + 1 < nT);
            if (pf) stage_load((t + 1) * KVB);   // issue-early: overlap compute

            const int kv0 = t * KVB;
            char* const Ks = smem + cur * 16384;
            char* const Vs = Ks + 8192;

            if (kv0 <= qrow + 15) {   // wave-uniform: skip fully-masked tiles
                // ---- QK^T swapped: S^T[k][q], k=kv0+16kt+4g+r, q=qrow+c ----
                f32x4 st[4];
#pragma unroll
                for (int kt = 0; kt < 4; ++kt) st[kt] = (f32x4){0.f, 0.f, 0.f, 0.f};
                __builtin_amdgcn_s_setprio(1);
#pragma unroll
                for (int kt = 0; kt < 4; ++kt) {
                    half8_t kf0 = *(const half8_t*)(Ks + swz_off(kt * 16 + c, g * 16));
                    half8_t kf1 = *(const half8_t*)(Ks + swz_off(kt * 16 + c, 64 + g * 16));
                    st[kt] = __builtin_amdgcn_mfma_f32_16x16x32_f16(kf0, qf0, st[kt], 0, 0, 0);
                    st[kt] = __builtin_amdgcn_mfma_f32_16x16x32_f16(kf1, qf1, st[kt], 0, 0, 0);
                }
                __builtin_amdgcn_s_setprio(0);

                // ---- causal mask: tiles overlapping the diagonal ----
                if (kv0 + KVB - 1 > qrow) {
                    const int qq = qrow + c;
#pragma unroll
                    for (int kt = 0; kt < 4; ++kt)
#pragma unroll
                        for (int r = 0; r < 4; ++r)
                            if (kv0 + kt * 16 + g * 4 + r > qq) st[kt][r] = -1e30f;
                }

                // ---- online softmax (exp2 domain), max3 tree, defer-max ----
                float m0 = fmax3(st[0][0], st[0][1], st[0][2]);
                float m1 = fmax3(st[0][3], st[1][0], st[1][1]);
                float m2 = fmax3(st[1][2], st[1][3], st[2][0]);
                float m3 = fmax3(st[2][1], st[2][2], st[2][3]);
                float m4 = fmax3(st[3][0], st[3][1], st[3][2]);
                float tmax = fmaxf(fmax3(fmax3(m0, m1, m2), m3, m4), st[3][3]);
                tmax = fmaxf(tmax, __shfl_xor(tmax, 16));
                tmax = fmaxf(tmax, __shfl_xor(tmax, 32));
                if (!__all(tmax - m_run <= DEFER_THR)) {
                    const float mnew  = fmaxf(m_run, tmax);
                    const float alpha = __builtin_amdgcn_exp2f(m_run - mnew);
                    m_run = mnew;
                    l_run *= alpha;
#pragma unroll
                    for (int dt = 0; dt < 4; ++dt) oacc[dt] = oacc[dt] * alpha;
                }
                float tsum = 0.f;
                half4_t pfq[4];   // P^T f16, already in PV B-fragment layout
#pragma unroll
                for (int kt = 0; kt < 4; ++kt) {
#pragma unroll
                    for (int r = 0; r < 4; ++r) {
                        float p = __builtin_amdgcn_exp2f(st[kt][r] - m_run);
                        tsum += p;
                        st[kt][r] = p;
                    }
                    pfq[kt] = cvt4(st[kt]);
                }
                l_run += tsum;    // per-lane partial; reduced in epilogue

                // ---- PV: O^T += V^T . P^T via 16x16x16 f16 ----
                __builtin_amdgcn_s_setprio(1);
#pragma unroll
                for (int ks = 0; ks < 4; ++ks) {
                    half4_t vf[4];
#pragma unroll
                    for (int dt = 0; dt < 4; ++dt)  // A: V^T[16dt+c][16ks+4g+j]
                        vf[dt] = *(const half4_t*)(Vs + vswz(dt * 16 + c, ks * 32 + g * 8));
#pragma unroll
                    for (int dt = 0; dt < 4; ++dt)
                        oacc[dt] = __builtin_amdgcn_mfma_f32_16x16x16f16(vf[dt], pfq[ks], oacc[dt], 0, 0, 0);
                }
                __builtin_amdgcn_s_setprio(0);
            }

            if (pf) stage_write(smem + (cur ^ 1) * 16384);   // write-late
            cur ^= 1;
        }

        // ---- epilogue: reduce l across g-groups, normalize, store ----
        float lr = l_run;
        lr += __shfl_xor(lr, 16);
        lr += __shfl_xor(lr, 32);
        const float inv = __builtin_amdgcn_rcpf(lr);
        float* optr = Op + (size_t)(qrow + c) * DH;
#pragma unroll
        for (int dt = 0; dt < 4; ++dt) {
            f32x4 o = oacc[dt] * inv;
            *(f32x4*)(optr + dt * 16 + g * 4) = o;
        }
    }
}

extern "C" void kernel_launch(void* const* d_in, const int* in_sizes, int n_in,
                              void* d_out, int out_size, void* d_ws, size_t ws_size,
                              hipStream_t stream) {
    (void)in_sizes; (void)n_in; (void)out_size; (void)d_ws; (void)ws_size;
    const float* Q = (const float*)d_in[0];
    const float* K = (const float*)d_in[1];
    const float* V = (const float*)d_in[2];
    float* O = (float*)d_out;
    dim3 grid(64, NQB / 2);   // 64 heads x 8 balanced q-block pairs
    fattn_kernel<<<grid, 512, 0, stream>>>(Q, K, V, O);
}